// Round 10
// baseline (207.827 us; speedup 1.0000x reference)
//
#include <hip/hip_runtime.h>

// Head: fused single-head causal attention. Round 12 RESUBMIT (round 9's
// bench was an infra failure: "container failed twice" — no counters, no
// kernel signal). DIAGNOSTIC round: rounds 5-11's four orthogonal
// structural changes (prefetch depth, softmax shortening, VGPR shave,
// cooperative 4-wave block) were all neutral at head ~61-64us vs a 26.6us
// traffic floor — and head_fused has never surfaced in the top-5 counter
// table unspilled. This round reps each element TWICE (identical output
// written both times; no race: same block, same values) to push head's dur
// above the ~78us fill dispatches and surface its real counters
// (Occupancy/VALUBusy/MfmaUtil/bank-conflicts/FETCH). rep1's x-loads are
// cache-hot, so delta-dur isolates memory vs internal cost:
//   head in [75,95]us   -> phase-1 stream-bound (rep1 cheap)
//   head in [105,130]us -> internal limiter; counters name it.
// Structure is otherwise byte-identical to round 11 (cooperative 4-wave
// block, LDS weights, P-strip aliasing, ones-MFMA row-sum softmax).
//
// mfma_f32_16x16x32_bf16 layouts (HW-verified, guide §3):
//   A-frag: A[m = lane&15][k = quad*8 + j]
//   B-frag: B[k = quad*8 + j][n = lane&15]
//   C/D   : col = lane&15, row = quad*4 + reg

#define TT 64
#define CC 128
#define HD 32

typedef __bf16 bf16_t;
typedef __bf16 bf8_t __attribute__((ext_vector_type(8)));
typedef __bf16 bf4_t __attribute__((ext_vector_type(4)));
typedef float  f4_t  __attribute__((ext_vector_type(4)));

// d_ws: wf[(n6*4 + kk)*64 + lane] = 16-byte bf8 B-frag.
// n6 = 0..5 (q lo/hi, k lo/hi, v lo/hi), kk = 0..3 (K blocks of 32).
// Element j = Wsel[(kk*32 + (lane>>4)*8 + j)][(n6&1)*16 + (lane&15)].
// Q-frags (n6<2) pre-scaled by 1/sqrt(32).
__global__ __launch_bounds__(256) void prep_weights(
    const float* __restrict__ Wq, const float* __restrict__ Wk,
    const float* __restrict__ Wv, bf16_t* __restrict__ wf)
{
  int t = blockIdx.x * 256 + threadIdx.x;   // 0..12287
  int j    = t & 7;
  int lane = (t >> 3) & 63;
  int kt   = (t >> 9) & 3;
  int n6   = t >> 11;
  int k    = kt * 32 + (lane >> 4) * 8 + j;
  int col  = (n6 & 1) * 16 + (lane & 15);
  const float* W = (n6 >> 1) == 0 ? Wq : ((n6 >> 1) == 1 ? Wk : Wv);
  float v = W[k * HD + col];
  if (n6 < 2) v *= 0.17677669529663687f;    // fold 1/sqrt(32) into Wq
  wf[t] = (bf16_t)v;
}

__global__ __launch_bounds__(256) void head_fused(
    const float* __restrict__ x, const float4* __restrict__ wf,
    float* __restrict__ out)
{
  __shared__ __align__(16) bf16_t wlds[12288];  // 24576 B weights; phase 2:
                                                //   first 9216 B = P strips
  __shared__ __align__(16) bf16_t ks[TT][40];   // k[row][d]        5120 B
  __shared__ __align__(16) bf16_t vt[HD][72];   // v^T[d][row]      4608 B
  // total 34304 B -> 4 blocks/CU by LDS

  const int tid  = threadIdx.x;
  const int wv   = tid >> 6;         // wave 0..3 = tile index within element
  const int lane = tid & 63;
  const int quad = lane >> 4;
  const int l16  = lane & 15;
  const int b    = blockIdx.x;       // one block per batch element
  const float* __restrict__ xblk = x + (size_t)b * (TT * CC);
  float* __restrict__ ob = out + (size_t)b * (TT * HD);

  const f4_t zero4 = {0.f, 0.f, 0.f, 0.f};

  float4 qf[2];                      // quarter-tile x staging (8 VGPR)

  // wave loads quarters of ITS 16-row tile: lane covers 32 B of row 16wv+l16
  auto load_q = [&](int p) {
    const float* s = xblk + (16 * wv + l16) * CC + p * 32 + quad * 8;
    qf[0] = *(const float4*)s;
    qf[1] = *(const float4*)(s + 4);
  };
  auto cvtq = [&]() -> bf8_t {       // waits on qf, frees it for re-issue
    float4 f0 = qf[0], f1 = qf[1];
    bf8_t a;
    a[0] = (bf16_t)f0.x; a[1] = (bf16_t)f0.y; a[2] = (bf16_t)f0.z; a[3] = (bf16_t)f0.w;
    a[4] = (bf16_t)f1.x; a[5] = (bf16_t)f1.y; a[6] = (bf16_t)f1.z; a[7] = (bf16_t)f1.w;
    return a;
  };
  // weight frag t: conflict-free ds_read_b128 (lane*16 B contiguous)
  auto wfrag = [&](int t) -> bf8_t {
    return *(const bf8_t*)&wlds[t * 512 + lane * 8];
  };

  // ======== DIAGNOSTIC rep loop: element executed twice, same output ========
  for (int rep = 0; rep < 2; ++rep) {
    // ---- issue first x quarter, then stage weights to LDS ----
    load_q(0);
    #pragma unroll
    for (int u = 0; u < 6; ++u) {                // 6 x (256 thr x 16 B) = 24 KB
      float4 w4 = wf[u * 256 + tid];
      *(float4*)&wlds[(size_t)(u * 256 + tid) * 8] = w4;
    }
    __syncthreads();                 // weights visible to all waves

    // ---------------- phase 1: each wave projects its own tile ----------------
    f4_t acc[6];
    #pragma unroll
    for (int n = 0; n < 6; ++n) acc[n] = zero4;
    #pragma unroll
    for (int p = 0; p < 4; ++p) {
      bf8_t a = cvtq();                        // WAR on qf keeps order safe
      if (p < 3) load_q(p + 1);                // re-issue freed buffer
      #pragma unroll
      for (int n = 0; n < 6; ++n)
        acc[n] = __builtin_amdgcn_mfma_f32_16x16x32_bf16(a, wfrag(n * 4 + p), acc[n], 0, 0, 0);
    }
    // k -> ks, v -> vt (shared); q stays in registers as bf16 C-frags
    #pragma unroll
    for (int r = 0; r < 4; ++r) {
      int row = 16 * wv + quad * 4 + r;        // C/D: row = quad*4 + reg
      ks[row][l16]      = (bf16_t)acc[2][r];
      ks[row][16 + l16] = (bf16_t)acc[3][r];
    }
    bf4_t v0 = { (bf16_t)acc[4][0], (bf16_t)acc[4][1], (bf16_t)acc[4][2], (bf16_t)acc[4][3] };
    bf4_t v1 = { (bf16_t)acc[5][0], (bf16_t)acc[5][1], (bf16_t)acc[5][2], (bf16_t)acc[5][3] };
    *(bf4_t*)&vt[l16][16 * wv + quad * 4]      = v0;   // tokens quad*4..+3 contiguous
    *(bf4_t*)&vt[16 + l16][16 * wv + quad * 4] = v1;
    bf4_t qc0 = { (bf16_t)acc[0][0], (bf16_t)acc[0][1], (bf16_t)acc[0][2], (bf16_t)acc[0][3] };
    bf4_t qc1 = { (bf16_t)acc[1][0], (bf16_t)acc[1][1], (bf16_t)acc[1][2], (bf16_t)acc[1][3] };
    __syncthreads();                 // k/v visible; weight region now dead

    // ---------------- phase 2: wave wv runs sm_tile(wv) ----------------
    // P strip aliases the (dead) weight LDS: 4 x [16][72] x 2 B = 9216 B
    bf16_t* __restrict__ psw = wlds + wv * 1152;

    // q C-layout -> A-frag via own strip (in-order DS within the wave)
    #pragma unroll
    for (int r = 0; r < 4; ++r) {
      psw[(quad * 4 + r) * 72 + l16]      = qc0[r];
      psw[(quad * 4 + r) * 72 + 16 + l16] = qc1[r];
    }
    bf8_t aq = *(const bf8_t*)&psw[l16 * 72 + quad * 8];   // scale pre-folded

    bf8_t ones8;
    #pragma unroll
    for (int t = 0; t < 8; ++t) ones8[t] = (bf16_t)1.0f;

    const int i = wv;
    f4_t sc[4];
    #pragma unroll
    for (int j = 0; j < 4; ++j) {
      sc[j] = zero4;
      if (j <= i) {
        bf8_t bk = *(const bf8_t*)&ks[16 * j + l16][quad * 8];
        sc[j] = __builtin_amdgcn_mfma_f32_16x16x32_bf16(aq, bk, zero4, 0, 0, 0);
      }
    }
    #pragma unroll
    for (int r = 0; r < 4; ++r) {
      int rl = quad * 4 + r;
      #pragma unroll
      for (int j = 0; j < 4; ++j) {
        if (j <= i) {
          // no max-sub: |s| <= ~3 analytically, exp is safe; store raw exp
          bool valid = (j < i) | (l16 <= rl);  // diagonal-tile causal mask
          float e = __expf(sc[j][r]);
          psw[rl * 72 + j * 16 + l16] = (bf16_t)(valid ? e : 0.f);
        } else if (j == (i | 1)) {
          psw[rl * 72 + j * 16 + l16] = (bf16_t)0.f;  // zero-fill read range
        }
      }
    }
    f4_t o0 = zero4, o1 = zero4, osum = zero4;
    #pragma unroll
    for (int kk = 0; kk < 2; ++kk) {
      if (kk <= (i >> 1)) {                    // skip all-zero K-tiles for i<2
        int k0 = kk * 32 + quad * 8;
        bf8_t ap  = *(const bf8_t*)&psw[l16 * 72 + k0];
        bf8_t bv0 = *(const bf8_t*)&vt[l16][k0];
        bf8_t bv1 = *(const bf8_t*)&vt[16 + l16][k0];
        o0   = __builtin_amdgcn_mfma_f32_16x16x32_bf16(ap, bv0, o0, 0, 0, 0);
        o1   = __builtin_amdgcn_mfma_f32_16x16x32_bf16(ap, bv1, o1, 0, 0, 0);
        // D[m][n] = rowsum[m] for every n: each lane gets its row's denominator
        osum = __builtin_amdgcn_mfma_f32_16x16x32_bf16(ap, ones8, osum, 0, 0, 0);
      }
    }
    #pragma unroll
    for (int r = 0; r < 4; ++r) {
      int row = 16 * i + quad * 4 + r;
      float inv = __builtin_amdgcn_rcpf(osum[r]);   // >= exp(diag) > 0
      ob[row * HD + l16]      = o0[r] * inv;        // rep1 rewrites same bytes
      ob[row * HD + 16 + l16] = o1[r] * inv;
    }
    __syncthreads();                 // protect wlds/ks/vt before next rep's staging
  }
}

extern "C" void kernel_launch(void* const* d_in, const int* in_sizes, int n_in,
                              void* d_out, int out_size, void* d_ws, size_t ws_size,
                              hipStream_t stream) {
  const float* x  = (const float*)d_in[0];
  const float* Wq = (const float*)d_in[1];
  const float* Wk = (const float*)d_in[2];
  const float* Wv = (const float*)d_in[3];
  float* out = (float*)d_out;
  bf16_t* wf = (bf16_t*)d_ws;                  // 12288 bf16 = 24 KB
  int B = in_sizes[0] / (TT * CC);             // 4096

  prep_weights<<<dim3(48), dim3(256), 0, stream>>>(Wq, Wk, Wv, wf);
  head_fused<<<dim3(B), dim3(256), 0, stream>>>(x, (const float4*)wf, out);
}